// Round 1
// baseline (338.427 us; speedup 1.0000x reference)
//
#include <hip/hip_runtime.h>

#define N_NODES 100000
#define N_EDGES 1600000
#define D 64

#define SCAN_BLK 1024
#define NSCAN 98              // ceil(100000 / 1024)
#define EDGE_BLKS 782         // ceil(1600000 / 2048), 8 edges/thread @ 256 thr

__device__ __forceinline__ unsigned short f2bf(float f) {   // RNE float->bf16
    unsigned int u = __float_as_uint(f);
    u += 0x7FFFu + ((u >> 16) & 1u);
    return (unsigned short)(u >> 16);
}
__device__ __forceinline__ float bf2f(unsigned short u) {
    return __uint_as_float(((unsigned int)u) << 16);
}

// ---- pass 1: per-row edge count + w15 sum in ONE packed u64 atomic -------
// deg[r]: hi32 = count, lo32 = sum of w15  (max ~64*32767 << 2^32, no carry)
__global__ __launch_bounds__(256) void deg_k(const int* __restrict__ ei,
                                             const float* __restrict__ ew,
                                             unsigned long long* __restrict__ deg) {
    int base = blockIdx.x * 2048 + threadIdx.x;
#pragma unroll
    for (int k = 0; k < 8; ++k) {
        int e = base + k * 256;
        if (e < N_EDGES) {
            int r = __builtin_nontemporal_load(&ei[e]);
            float w = __builtin_nontemporal_load(&ew[e]);
            unsigned int w15 = (unsigned int)__float2int_rn(w * 32767.0f);
            atomicAdd(&deg[r], (1ULL << 32) | (unsigned long long)w15);
        }
    }
}

// ---- scan stage 1: per-1024-block count reduction ------------------------
__global__ __launch_bounds__(SCAN_BLK) void scan1_k(const unsigned long long* __restrict__ deg,
                                                    int* __restrict__ bsum) {
    __shared__ int ts[SCAN_BLK];
    int t = threadIdx.x;
    int idx = blockIdx.x * SCAN_BLK + t;
    ts[t] = (idx < N_NODES) ? (int)(deg[idx] >> 32) : 0;
    __syncthreads();
    for (int off = SCAN_BLK / 2; off > 0; off >>= 1) {
        if (t < off) ts[t] += ts[t + off];
        __syncthreads();
    }
    if (t == 0) bsum[blockIdx.x] = ts[0];
}

// ---- scan stage 2: exclusive scan of 98 block sums -----------------------
__global__ __launch_bounds__(128) void scan2_k(const int* __restrict__ bsum,
                                               int* __restrict__ boff) {
    __shared__ int ts[128];
    int t = threadIdx.x;
    int own = (t < NSCAN) ? bsum[t] : 0;
    ts[t] = own;
    __syncthreads();
    for (int off = 1; off < 128; off <<= 1) {
        int v = (t >= off) ? ts[t - off] : 0;
        __syncthreads();
        ts[t] += v;
        __syncthreads();
    }
    if (t < NSCAN) boff[t] = ts[t] - own;
}

// ---- scan stage 3: local exclusive scan + offset -> row_ptr; fused dinv --
__global__ __launch_bounds__(SCAN_BLK) void scan3_k(const unsigned long long* __restrict__ deg,
                                                    const int* __restrict__ boff,
                                                    int* __restrict__ row_ptr,
                                                    float* __restrict__ dinv) {
    __shared__ int ts[SCAN_BLK];
    int t = threadIdx.x;
    int idx = blockIdx.x * SCAN_BLK + t;
    unsigned long long d = (idx < N_NODES) ? deg[idx] : 0ULL;
    int c = (int)(d >> 32);
    ts[t] = c;
    __syncthreads();
    for (int off = 1; off < SCAN_BLK; off <<= 1) {
        int v = (t >= off) ? ts[t - off] : 0;
        __syncthreads();
        ts[t] += v;
        __syncthreads();
    }
    if (idx < N_NODES) {
        row_ptr[idx] = boff[blockIdx.x] + ts[t] - c;   // exclusive start
        unsigned int ws = (unsigned int)(d & 0xFFFFFFFFu);
        dinv[idx] = rsqrtf(1.0f + (float)ws * (1.0f / 32767.0f));
    }
}

// ---- pass 2: scatter edges into CSR slots via atomic slot grab -----------
// NOTE: consumes row_ptr destructively: after this, row_ptr[r] == start[r+1].
// gather reads start as row_ptr[n-1] (0 for n==0). Exact (no BIN_CAP clip).
__global__ __launch_bounds__(256) void scatter_k(const int* __restrict__ ei,
                                                 const float* __restrict__ ew,
                                                 int* __restrict__ row_ptr,
                                                 unsigned int* __restrict__ csr) {
    int base = blockIdx.x * 2048 + threadIdx.x;
#pragma unroll
    for (int k = 0; k < 8; ++k) {
        int e = base + k * 256;
        if (e < N_EDGES) {
            int r = __builtin_nontemporal_load(&ei[e]);
            int c = __builtin_nontemporal_load(&ei[N_EDGES + e]);
            float w = __builtin_nontemporal_load(&ew[e]);
            unsigned int w15 = (unsigned int)__float2int_rn(w * 32767.0f);
            int pos = atomicAdd(&row_ptr[r], 1);
            csr[pos] = (w15 << 17) | (unsigned int)c;
        }
    }
}

// ---------------------- y' = dinv .* (X * W^T), stored bf16 ---------------
__global__ __launch_bounds__(256) void xw_k(const float* __restrict__ x,
                                            const float* __restrict__ W,
                                            const float* __restrict__ dinv,
                                            unsigned short* __restrict__ yp) {
    __shared__ float xsT[64][68];   // [k][node]
    __shared__ float Wt[64][68];    // [k][feat]
    int tid = threadIdx.x;
    int nbase = blockIdx.x * 64;
#pragma unroll
    for (int r = 0; r < 4; ++r) {   // W: [j][k] row-major, 4096 floats
        int idx = r * 1024 + tid * 4;
        int j = idx >> 6, k = idx & 63;
        float4 v = *(const float4*)(W + idx);
        Wt[k + 0][j] = v.x; Wt[k + 1][j] = v.y; Wt[k + 2][j] = v.z; Wt[k + 3][j] = v.w;
    }
#pragma unroll
    for (int r = 0; r < 4; ++r) {   // x block, transposed into LDS
        int idx = r * 1024 + tid * 4;
        int nl = idx >> 6, k = idx & 63;
        int n = nbase + nl;
        float4 v = (n < N_NODES) ? *(const float4*)(x + n * 64 + k)
                                 : make_float4(0.f, 0.f, 0.f, 0.f);
        xsT[k + 0][nl] = v.x; xsT[k + 1][nl] = v.y; xsT[k + 2][nl] = v.z; xsT[k + 3][nl] = v.w;
    }
    __syncthreads();

    int tx = tid & 15;          // feature group: j0 = tx*4
    int ty = tid >> 4;          // node group:    n0 = ty*4
    float acc[4][4];
#pragma unroll
    for (int i = 0; i < 4; ++i)
#pragma unroll
        for (int j = 0; j < 4; ++j) acc[i][j] = 0.f;

#pragma unroll 8
    for (int k = 0; k < 64; ++k) {
        float4 a = *(const float4*)&xsT[k][ty * 4];
        float4 w = *(const float4*)&Wt[k][tx * 4];
        float av[4] = {a.x, a.y, a.z, a.w};
        float wv[4] = {w.x, w.y, w.z, w.w};
#pragma unroll
        for (int i = 0; i < 4; ++i)
#pragma unroll
            for (int j = 0; j < 4; ++j) acc[i][j] += av[i] * wv[j];
    }
#pragma unroll
    for (int i = 0; i < 4; ++i) {
        int n = nbase + ty * 4 + i;
        if (n < N_NODES) {
            float di = dinv[n];
            ushort4 v;
            v.x = f2bf(di * acc[i][0]);
            v.y = f2bf(di * acc[i][1]);
            v.z = f2bf(di * acc[i][2]);
            v.w = f2bf(di * acc[i][3]);
            *(ushort4*)(yp + n * 64 + tx * 4) = v;   // 8B store
        }
    }
}

// ---- gather: 1 wave per row; wave-cooperative CSR fetch + readlane --------
// out = dinv[r]*(y'[r] + (1/32767)*Σ w15·y'[c]) + b   (y' carries dinv factor)
__global__ __launch_bounds__(256) void gather_k(const int* __restrict__ row_ptr,
                                                const float* __restrict__ dinv,
                                                const unsigned int* __restrict__ csr,
                                                const unsigned short* __restrict__ yp,
                                                const float* __restrict__ b,
                                                float* __restrict__ out) {
    int wv = threadIdx.x >> 6;
    int lane = threadIdx.x & 63;
    int n = blockIdx.x * 4 + wv;          // grid covers exactly 100000

    // post-scatter semantics: row_ptr[n] == start[n+1]
    int e_ = row_ptr[n];
    int s = (n == 0) ? 0 : row_ptr[n - 1];
    int cnt = e_ - s;
    float self = bf2f(yp[n * D + lane]);  // self-loop term
    float acc0 = 0.f, acc1 = 0.f;         // dual accumulators: break FMA chain

    for (int base = 0; base < cnt; base += 64) {
        int m = cnt - base; if (m > 64) m = 64;
        // one coalesced load fetches up to 64 records for this row
        unsigned int rec = (lane < m) ? csr[s + base + lane] : 0u;
        int r = 0;
        for (; r + 7 < m; r += 8) {
            unsigned int u[8];
#pragma unroll
            for (int q = 0; q < 8; ++q)
                u[q] = __builtin_amdgcn_readlane(rec, r + q);
            float yv[8];
#pragma unroll
            for (int q = 0; q < 8; ++q)
                yv[q] = bf2f(yp[(u[q] & 0x1FFFFu) * D + lane]);
#pragma unroll
            for (int q = 0; q < 8; ++q) {
                float wf = (float)(u[q] >> 17);          // scale hoisted out
                if (q & 1) acc1 += wf * yv[q];
                else       acc0 += wf * yv[q];
            }
        }
        for (; r < m; ++r) {
            unsigned int u = __builtin_amdgcn_readlane(rec, r);
            acc0 += (float)(u >> 17) * bf2f(yp[(u & 0x1FFFFu) * D + lane]);
        }
    }

    float o = dinv[n] * (self + (acc0 + acc1) * (1.0f / 32767.0f)) + b[lane];
    __builtin_nontemporal_store(o, &out[n * D + lane]);
}

// ---------------------------------------------------------------------------
extern "C" void kernel_launch(void* const* d_in, const int* in_sizes, int n_in,
                              void* d_out, int out_size, void* d_ws, size_t ws_size,
                              hipStream_t stream) {
    const float* x  = (const float*)d_in[0];
    const int*   ei = (const int*)d_in[1];     // [2, E]
    const float* ew = (const float*)d_in[2];
    const float* W  = (const float*)d_in[3];
    const float* b  = (const float*)d_in[4];
    float* out = (float*)d_out;

    char* ws = (char*)d_ws;
    unsigned long long* deg     = (unsigned long long*) ws;                  // 802,816 B
    int*                bsum    = (int*)               (ws + 0x100000);      // 392 B
    int*                boff    = (int*)               (ws + 0x101000);      // 392 B
    int*                row_ptr = (int*)               (ws + 0x110000);      // 400 KB
    float*              dinv    = (float*)             (ws + 0x180000);      // 400 KB
    unsigned short*     yp      = (unsigned short*)    (ws + 0x200000);      // 12.8 MB
    unsigned int*       csr     = (unsigned int*)      (ws + 0xF00000);      // 6.4 MB (end ~22 MB)

    hipMemsetAsync(deg, 0, (size_t)NSCAN * SCAN_BLK * sizeof(unsigned long long), stream);
    deg_k    <<<EDGE_BLKS, 256, 0, stream>>>(ei, ew, deg);
    scan1_k  <<<NSCAN, SCAN_BLK, 0, stream>>>(deg, bsum);
    scan2_k  <<<1, 128, 0, stream>>>(bsum, boff);
    scan3_k  <<<NSCAN, SCAN_BLK, 0, stream>>>(deg, boff, row_ptr, dinv);
    scatter_k<<<EDGE_BLKS, 256, 0, stream>>>(ei, ew, row_ptr, csr);
    xw_k     <<<(N_NODES + 63) / 64, 256, 0, stream>>>(x, W, dinv, yp);
    gather_k <<<N_NODES / 4, 256, 0, stream>>>(row_ptr, dinv, csr, yp, b, out);
}